// Round 1
// baseline (1491.424 us; speedup 1.0000x reference)
//
#include <hip/hip_runtime.h>
#include <math.h>

namespace {

constexpr int D  = 768;
constexpr int H  = 12;
constexpr int DK = 64;
constexpr int B  = 8;
constexpr int LM = 512;
constexpr int LP = 1024;

__device__ inline float wave_reduce_sum(float v) {
#pragma unroll
  for (int o = 1; o < 64; o <<= 1) v += __shfl_xor(v, o, 64);
  return v;
}
__device__ inline float wave_reduce_max(float v) {
#pragma unroll
  for (int o = 1; o < 64; o <<= 1) v = fmaxf(v, __shfl_xor(v, o, 64));
  return v;
}

// ---------------------------------------------------------------------------
// Generic fp32 GEMM: C[M,N] = A[M,K] * B[K,N] (+bias) (+exact gelu)
// 128x128 tile, BK=32, 256 threads, 8x8 per thread.
// EPI: 0=none, 1=+bias, 2=+bias then gelu(exact)
// All of M,N,K are multiples of the tile dims for every call site.
// ---------------------------------------------------------------------------
template <int EPI>
__global__ __launch_bounds__(256) void gemm128(const float* __restrict__ A,
                                               const float* __restrict__ Bm,
                                               const float* __restrict__ bias,
                                               float* __restrict__ C,
                                               int M, int N, int K) {
  __shared__ float As[32][132];  // [k][m] (transposed on store)
  __shared__ float Bs[32][132];  // [k][n]
  const int tid = threadIdx.x;
  const int bm = blockIdx.y * 128;
  const int bn = blockIdx.x * 128;
  const int tx = tid & 15, ty = tid >> 4;

  float acc[8][8];
#pragma unroll
  for (int i = 0; i < 8; ++i)
#pragma unroll
    for (int j = 0; j < 8; ++j) acc[i][j] = 0.f;

  for (int k0 = 0; k0 < K; k0 += 32) {
#pragma unroll
    for (int it = 0; it < 4; ++it) {
      int lin = tid + it * 256;       // 0..1023
      int row = lin >> 3;             // 0..127
      int c4  = (lin & 7) << 2;       // 0..28
      float4 v = *(const float4*)(A + (size_t)(bm + row) * K + k0 + c4);
      As[c4 + 0][row] = v.x; As[c4 + 1][row] = v.y;
      As[c4 + 2][row] = v.z; As[c4 + 3][row] = v.w;
    }
#pragma unroll
    for (int it = 0; it < 4; ++it) {
      int lin = tid + it * 256;
      int row = lin >> 5;             // 0..31
      int c4  = (lin & 31) << 2;      // 0..124
      *(float4*)&Bs[row][c4] =
          *(const float4*)(Bm + (size_t)(k0 + row) * N + bn + c4);
    }
    __syncthreads();
#pragma unroll
    for (int kk = 0; kk < 32; ++kk) {
      float a[8], b[8];
      *(float4*)&a[0] = *(const float4*)&As[kk][ty * 8];
      *(float4*)&a[4] = *(const float4*)&As[kk][ty * 8 + 4];
      *(float4*)&b[0] = *(const float4*)&Bs[kk][tx * 8];
      *(float4*)&b[4] = *(const float4*)&Bs[kk][tx * 8 + 4];
#pragma unroll
      for (int i = 0; i < 8; ++i)
#pragma unroll
        for (int j = 0; j < 8; ++j) acc[i][j] = fmaf(a[i], b[j], acc[i][j]);
    }
    __syncthreads();
  }

#pragma unroll
  for (int i = 0; i < 8; ++i) {
    size_t r = bm + ty * 8 + i;
    float out[8];
#pragma unroll
    for (int j = 0; j < 8; ++j) {
      float v = acc[i][j];
      if (EPI >= 1) v += bias[bn + tx * 8 + j];
      if (EPI == 2) v = 0.5f * v * (1.0f + erff(v * 0.70710678118654752f));
      out[j] = v;
    }
    *(float4*)(C + r * N + bn + tx * 8)     = *(float4*)&out[0];
    *(float4*)(C + r * N + bn + tx * 8 + 4) = *(float4*)&out[4];
  }
}

// ---------------------------------------------------------------------------
// Scores: S[b,h,q,k] = (1/8) * sum_dd Q[b,q,h*64+dd] * K[b,k,h*64+dd]
// 64(q) x 64(k) tile per block, inner dim 64 in one shot.
// grid: (LP/64, LM/64, B*H)
// ---------------------------------------------------------------------------
__global__ __launch_bounds__(256) void scores_kernel(const float* __restrict__ Q,
                                                     const float* __restrict__ Kmat,
                                                     float* __restrict__ S) {
  __shared__ float Qs[64][68];  // [dd][q] transposed
  __shared__ float Ks[64][68];  // [k][dd]
  const int bh = blockIdx.z;
  const int b = bh / H, h = bh % H;
  const int q0 = blockIdx.y * 64;
  const int k0 = blockIdx.x * 64;
  const float* Qb = Q + (size_t)(b * LM + q0) * D + h * DK;
  const float* Kb = Kmat + (size_t)(b * LP + k0) * D + h * DK;
  const int tid = threadIdx.x;
#pragma unroll
  for (int it = 0; it < 4; ++it) {
    int lin = tid + it * 256;   // 0..1023
    int row = lin >> 4;         // 0..63
    int c4  = (lin & 15) << 2;  // 0..60
    float4 q = *(const float4*)(Qb + (size_t)row * D + c4);
    Qs[c4 + 0][row] = q.x; Qs[c4 + 1][row] = q.y;
    Qs[c4 + 2][row] = q.z; Qs[c4 + 3][row] = q.w;
    *(float4*)&Ks[row][c4] = *(const float4*)(Kb + (size_t)row * D + c4);
  }
  __syncthreads();
  const int tx = tid & 15, ty = tid >> 4;
  float acc[4][4] = {};
#pragma unroll
  for (int kk = 0; kk < 64; ++kk) {
    float a[4], bb[4];
    *(float4*)&a[0] = *(const float4*)&Qs[kk][ty * 4];
#pragma unroll
    for (int j = 0; j < 4; ++j) bb[j] = Ks[tx * 4 + j][kk];
#pragma unroll
    for (int i = 0; i < 4; ++i)
#pragma unroll
      for (int j = 0; j < 4; ++j) acc[i][j] = fmaf(a[i], bb[j], acc[i][j]);
  }
  const float scale = 0.125f;  // 1/sqrt(64)
#pragma unroll
  for (int i = 0; i < 4; ++i) {
    float out[4];
#pragma unroll
    for (int j = 0; j < 4; ++j) out[j] = acc[i][j] * scale;
    *(float4*)(S + ((size_t)bh * LM + q0 + ty * 4 + i) * LP + k0 + tx * 4) =
        *(float4*)&out[0];
  }
}

// ---------------------------------------------------------------------------
// Masked softmax, in place on (B*H*LM, LP) rows. mask[b][k]!=0 => -inf.
// all-masked guard: if every key of batch b is masked, unmask key 0.
// One block (256 thr) per row, 4 elements/thread.
// ---------------------------------------------------------------------------
__global__ __launch_bounds__(256) void softmax_kernel(float* __restrict__ attnp,
                                                      const int* __restrict__ mask) {
  const int row = blockIdx.x;  // bh*LM + q
  const int b = row / (H * LM);
  float* p = attnp + (size_t)row * LP;
  const int* mrow = mask + b * LP;
  const int tid = threadIdx.x;

  bool mk[4]; float s[4];
  bool anyun = false;
#pragma unroll
  for (int t = 0; t < 4; ++t) {
    int k = tid + t * 256;
    mk[t] = mrow[k] != 0;
    anyun |= !mk[t];
    s[t] = p[k];
  }
  __shared__ int allm_s;
  if (tid == 0) allm_s = 1;
  __syncthreads();
  if (anyun) allm_s = 0;  // benign race: all writers store 0
  __syncthreads();
  if (allm_s && tid == 0) mk[0] = false;  // key 0 of this row

  float m = -INFINITY;
#pragma unroll
  for (int t = 0; t < 4; ++t)
    if (!mk[t]) m = fmaxf(m, s[t]);
  __shared__ float red[4];
  m = wave_reduce_max(m);
  if ((tid & 63) == 0) red[tid >> 6] = m;
  __syncthreads();
  m = fmaxf(fmaxf(red[0], red[1]), fmaxf(red[2], red[3]));
  __syncthreads();

  float e[4]; float sum = 0.f;
#pragma unroll
  for (int t = 0; t < 4; ++t) {
    e[t] = mk[t] ? 0.f : expf(s[t] - m);
    sum += e[t];
  }
  sum = wave_reduce_sum(sum);
  if ((tid & 63) == 0) red[tid >> 6] = sum;
  __syncthreads();
  sum = red[0] + red[1] + red[2] + red[3];
  const float inv = 1.0f / sum;
#pragma unroll
  for (int t = 0; t < 3 + 1; ++t) p[tid + t * 256] = e[t] * inv;
}

// ---------------------------------------------------------------------------
// PV: O[b, q, h*64+dd] = sum_k P[b,h,q,k] * V[b,k,h*64+dd]
// 64(q) x 64(dd) tile per block, BK=16.  grid: (LM/64, B*H)
// ---------------------------------------------------------------------------
__global__ __launch_bounds__(256) void pv_kernel(const float* __restrict__ P,
                                                 const float* __restrict__ V,
                                                 float* __restrict__ O) {
  __shared__ float Ps[16][68];  // [k][q] transposed
  __shared__ float Vs[16][68];  // [k][dd]
  const int bh = blockIdx.y;
  const int b = bh / H, h = bh % H;
  const int q0 = blockIdx.x * 64;
  const float* Pb = P + ((size_t)bh * LM + q0) * LP;
  const float* Vb = V + (size_t)b * LP * D + h * DK;
  const int tid = threadIdx.x;
  const int tx = tid & 15, ty = tid >> 4;
  float acc[4][4] = {};
  for (int k0 = 0; k0 < LP; k0 += 16) {
    {
      int row = tid >> 2;        // 0..63
      int c4  = (tid & 3) << 2;  // 0..12
      float4 v = *(const float4*)(Pb + (size_t)row * LP + k0 + c4);
      Ps[c4 + 0][row] = v.x; Ps[c4 + 1][row] = v.y;
      Ps[c4 + 2][row] = v.z; Ps[c4 + 3][row] = v.w;
      int vrow = tid >> 4;        // 0..15
      int vc4  = (tid & 15) << 2; // 0..60
      *(float4*)&Vs[vrow][vc4] =
          *(const float4*)(Vb + (size_t)(k0 + vrow) * D + vc4);
    }
    __syncthreads();
#pragma unroll
    for (int kk = 0; kk < 16; ++kk) {
      float a[4], bb[4];
      *(float4*)&a[0]  = *(const float4*)&Ps[kk][ty * 4];
      *(float4*)&bb[0] = *(const float4*)&Vs[kk][tx * 4];
#pragma unroll
      for (int i = 0; i < 4; ++i)
#pragma unroll
        for (int j = 0; j < 4; ++j) acc[i][j] = fmaf(a[i], bb[j], acc[i][j]);
    }
    __syncthreads();
  }
#pragma unroll
  for (int i = 0; i < 4; ++i)
    *(float4*)(O + (size_t)(b * LM + q0 + ty * 4 + i) * D + h * DK + tx * 4) =
        *(float4*)&acc[i][0];
}

// ---------------------------------------------------------------------------
// LayerNorm(out = LN(xa + xb) * g + be), one block per row of 768.
// ---------------------------------------------------------------------------
__global__ __launch_bounds__(256) void ln_kernel(const float* __restrict__ xa,
                                                 const float* __restrict__ xb,
                                                 const float* __restrict__ g,
                                                 const float* __restrict__ be,
                                                 float* __restrict__ out) {
  const int row = blockIdx.x;
  const float* pa = xa + (size_t)row * D;
  const float* pb = xb + (size_t)row * D;
  const int tid = threadIdx.x;
  float v[3]; float s = 0.f, ss = 0.f;
#pragma unroll
  for (int t = 0; t < 3; ++t) {
    int c = tid + t * 256;
    v[t] = pa[c] + pb[c];
    s += v[t]; ss += v[t] * v[t];
  }
  __shared__ float r1[4], r2[4];
  s = wave_reduce_sum(s);
  ss = wave_reduce_sum(ss);
  if ((tid & 63) == 0) { r1[tid >> 6] = s; r2[tid >> 6] = ss; }
  __syncthreads();
  s  = r1[0] + r1[1] + r1[2] + r1[3];
  ss = r2[0] + r2[1] + r2[2] + r2[3];
  const float mu  = s * (1.0f / D);
  const float var = ss * (1.0f / D) - mu * mu;
  const float inv = rsqrtf(var + 1e-5f);
#pragma unroll
  for (int t = 0; t < 3; ++t) {
    int c = tid + t * 256;
    out[(size_t)row * D + c] = (v[t] - mu) * inv * g[c] + be[c];
  }
}

}  // namespace

extern "C" void kernel_launch(void* const* d_in, const int* in_sizes, int n_in,
                              void* d_out, int out_size, void* d_ws, size_t ws_size,
                              hipStream_t stream) {
  const float* mol  = (const float*)d_in[0];
  const float* prot = (const float*)d_in[1];
  const int*   mask = (const int*)d_in[2];
  const float* Wq = (const float*)d_in[3];
  const float* Wk = (const float*)d_in[4];
  const float* Wv = (const float*)d_in[5];
  const float* Wo = (const float*)d_in[6];
  const float* bo = (const float*)d_in[7];
  const float* g1 = (const float*)d_in[8];
  const float* be1 = (const float*)d_in[9];
  const float* g2 = (const float*)d_in[10];
  const float* be2 = (const float*)d_in[11];
  const float* W1 = (const float*)d_in[12];
  const float* bf1 = (const float*)d_in[13];
  const float* W2 = (const float*)d_in[14];
  const float* bf2 = (const float*)d_in[15];

  float* outx = (float*)d_out;                       // (B,LM,D)
  float* attn = outx + (size_t)B * LM * D;           // (B,H,LM,LP)

  // workspace layout (floats). total 25,165,824 floats = 96 MiB.
  float* ws  = (float*)d_ws;
  float* Qb  = ws;                 // 4096x768
  float* Kb  = ws + 3145728;       // 8192x768
  float* Vb  = ws + 9437184;       // 8192x768
  float* AO  = ws + 15728640;      // 4096x768  attn out (pre-Wo)
  float* X1  = ws + 18874368;      // 4096x768  LN1 output
  float* FF  = ws + 22020096;      // 4096x768  FFN output
  float* HID = ws + 3145728;       // 4096x3072 aliases Kb+Vb (dead after PV)

  dim3 t(256);
  // Projections
  hipLaunchKernelGGL((gemm128<0>), dim3(6, 32), t, 0, stream, mol,  Wq, nullptr, Qb, B * LM, D, D);
  hipLaunchKernelGGL((gemm128<0>), dim3(6, 64), t, 0, stream, prot, Wk, nullptr, Kb, B * LP, D, D);
  hipLaunchKernelGGL((gemm128<0>), dim3(6, 64), t, 0, stream, prot, Wv, nullptr, Vb, B * LP, D, D);
  // Attention: scores straight into d_out attn region, softmax in place
  hipLaunchKernelGGL(scores_kernel, dim3(16, 8, 96), t, 0, stream, Qb, Kb, attn);
  hipLaunchKernelGGL(softmax_kernel, dim3(96 * 512), t, 0, stream, attn, mask);
  hipLaunchKernelGGL(pv_kernel, dim3(8, 96), t, 0, stream, attn, Vb, AO);
  // Output projection (into Qb, which is dead now) + LN1
  hipLaunchKernelGGL((gemm128<1>), dim3(6, 32), t, 0, stream, AO, Wo, bo, Qb, B * LM, D, D);
  hipLaunchKernelGGL(ln_kernel, dim3(4096), t, 0, stream, mol, Qb, g1, be1, X1);
  // FFN
  hipLaunchKernelGGL((gemm128<2>), dim3(24, 32), t, 0, stream, X1, W1, bf1, HID, B * LM, 4 * D, D);
  hipLaunchKernelGGL((gemm128<1>), dim3(6, 32), t, 0, stream, HID, W2, bf2, FF, B * LM, D, 4 * D);
  hipLaunchKernelGGL(ln_kernel, dim3(4096), t, 0, stream, X1, FF, g2, be2, outx);
}

// Round 2
// 432.420 us; speedup vs baseline: 3.4490x; 3.4490x over previous
//
#include <hip/hip_runtime.h>
#include <math.h>

namespace {

constexpr int D  = 768;
constexpr int H  = 12;
constexpr int DK = 64;
constexpr int B  = 8;
constexpr int LM = 512;
constexpr int LP = 1024;

typedef __attribute__((ext_vector_type(8))) short bf16x8;
typedef __attribute__((ext_vector_type(4))) float f32x4;
typedef unsigned short u16;

__device__ inline u16 f2bf(float f) {
  union { float f; unsigned u; } v;
  v.f = f;
  unsigned r = v.u + 0x7FFFu + ((v.u >> 16) & 1u);
  return (u16)(r >> 16);
}

__device__ inline void gload16(const void* g, void* l) {
  __builtin_amdgcn_global_load_lds((const __attribute__((address_space(1))) void*)g,
                                   (__attribute__((address_space(3))) void*)l,
                                   16, 0, 0);
}

__device__ inline float wave_reduce_sum(float v) {
#pragma unroll
  for (int o = 1; o < 64; o <<= 1) v += __shfl_xor(v, o, 64);
  return v;
}
__device__ inline float wave_reduce_max(float v) {
#pragma unroll
  for (int o = 1; o < 64; o <<= 1) v = fmaxf(v, __shfl_xor(v, o, 64));
  return v;
}

// ---------------------------------------------------------------------------
// bf16 MFMA GEMM, 128x128 tile, BK=64, 256 threads (4 waves, 2x2 of 64x64).
// A [M][ldA] bf16 row-major; Bt [N][ldB] bf16 row-major (i.e. B transposed).
// EPI: 0 none, 1 +bias, 2 +bias+gelu(exact).  OF32/OB16: output formats.
// BATCHED: per-(b,h) slices for the QK^T scores GEMM (z = b*H + h).
// ---------------------------------------------------------------------------
template <int EPI, bool OF32, bool OB16, bool BATCHED>
__global__ __launch_bounds__(256) void gemm_bf16(
    const u16* __restrict__ A, const u16* __restrict__ Bt,
    const float* __restrict__ bias, float* __restrict__ Cf,
    u16* __restrict__ Cb, int K, int ldA, int ldB, int ldC, float scale) {
  __shared__ u16 As[128 * 64];
  __shared__ u16 Bs[128 * 64];
  const int tid = threadIdx.x, wv = tid >> 6, lane = tid & 63;
  if (BATCHED) {
    const int z = blockIdx.z, b = z / H, h = z % H;
    A  += (size_t)b * LM * D + h * DK;
    Bt += (size_t)b * LP * D + h * DK;
    Cf += (size_t)z * LM * LP;
  }
  const int bm = blockIdx.y * 128, bn = blockIdx.x * 128;
  const int wr = (wv >> 1) * 64, wc = (wv & 1) * 64;

  f32x4 acc[4][4];
  const f32x4 z4 = {0.f, 0.f, 0.f, 0.f};
#pragma unroll
  for (int m = 0; m < 4; ++m)
#pragma unroll
    for (int n = 0; n < 4; ++n) acc[m][n] = z4;

  const u16* Ab = A + (size_t)(bm + wv * 32 + (lane >> 3)) * ldA + (lane & 7) * 8;
  const u16* Bb = Bt + (size_t)(bn + wv * 32 + (lane >> 3)) * ldB + (lane & 7) * 8;

  for (int k0 = 0; k0 < K; k0 += 64) {
#pragma unroll
    for (int i = 0; i < 4; ++i)
      gload16(Ab + (size_t)i * 8 * ldA + k0, &As[(wv * 32 + i * 8) * 64]);
#pragma unroll
    for (int i = 0; i < 4; ++i)
      gload16(Bb + (size_t)i * 8 * ldB + k0, &Bs[(wv * 32 + i * 8) * 64]);
    __syncthreads();
#pragma unroll
    for (int kk = 0; kk < 2; ++kk) {
      const int krd = kk * 32 + (lane >> 4) * 8;
      bf16x8 af[4], bfr[4];
#pragma unroll
      for (int m = 0; m < 4; ++m)
        af[m] = *(const bf16x8*)&As[(wr + m * 16 + (lane & 15)) * 64 + krd];
#pragma unroll
      for (int n = 0; n < 4; ++n)
        bfr[n] = *(const bf16x8*)&Bs[(wc + n * 16 + (lane & 15)) * 64 + krd];
#pragma unroll
      for (int m = 0; m < 4; ++m)
#pragma unroll
        for (int n = 0; n < 4; ++n)
          acc[m][n] =
              __builtin_amdgcn_mfma_f32_16x16x32_bf16(af[m], bfr[n], acc[m][n], 0, 0, 0);
    }
    __syncthreads();
  }

  const int r0 = bm + wr + (lane >> 4) * 4;
  const int c0 = bn + wc + (lane & 15);
#pragma unroll
  for (int m = 0; m < 4; ++m) {
#pragma unroll
    for (int n = 0; n < 4; ++n) {
      const int c = c0 + n * 16;
      const float bv = (EPI >= 1) ? bias[c] : 0.f;
#pragma unroll
      for (int j = 0; j < 4; ++j) {
        const int r = r0 + m * 16 + j;
        float v = acc[m][n][j] * scale + bv;
        if (EPI == 2) v = 0.5f * v * (1.f + erff(v * 0.70710678118654752f));
        if (OF32) Cf[(size_t)r * ldC + c] = v;
        if (OB16) Cb[(size_t)r * ldC + c] = f2bf(v);
      }
    }
  }
}

// ---------------------------------------------------------------------------
// PV: O[b,q,h*64+dd] = sum_k P[bh,q,k] * V[bh,k,dd];  Vt is [bh][64 dd][LP k].
// Tile 128(q) x 64(dd), BK=64; P (f32) is reg-staged and converted to bf16.
// grid: (LM/128, B*H)
// ---------------------------------------------------------------------------
__global__ __launch_bounds__(256) void pv_bf16(const float* __restrict__ P,
                                               const u16* __restrict__ Vt,
                                               u16* __restrict__ AOb) {
  __shared__ u16 Ps[128 * 64];
  __shared__ u16 Vs[64 * 64];
  const int tid = threadIdx.x, wv = tid >> 6, lane = tid & 63;
  const int zz = blockIdx.y, b = zz / H, h = zz % H;
  const int q0 = blockIdx.x * 128;
  const float* Pb = P + ((size_t)zz * LM + q0) * LP;
  const u16* Vb = Vt + (size_t)zz * 64 * LP;

  f32x4 acc[2][4];
  const f32x4 z4 = {0.f, 0.f, 0.f, 0.f};
#pragma unroll
  for (int m = 0; m < 2; ++m)
#pragma unroll
    for (int n = 0; n < 4; ++n) acc[m][n] = z4;

  const int prow = tid >> 1, pcol = (tid & 1) * 32;
  for (int k0 = 0; k0 < LP; k0 += 64) {
    {
      const float* src = Pb + (size_t)prow * LP + k0 + pcol;
      u16 tmp[32];
#pragma unroll
      for (int j = 0; j < 8; ++j) {
        float4 v = *(const float4*)(src + j * 4);
        tmp[j * 4 + 0] = f2bf(v.x);
        tmp[j * 4 + 1] = f2bf(v.y);
        tmp[j * 4 + 2] = f2bf(v.z);
        tmp[j * 4 + 3] = f2bf(v.w);
      }
#pragma unroll
      for (int j = 0; j < 4; ++j)
        *(int4*)&Ps[prow * 64 + pcol + j * 8] = *(const int4*)&tmp[j * 8];
    }
#pragma unroll
    for (int i = 0; i < 2; ++i)
      gload16(Vb + (size_t)(wv * 16 + i * 8 + (lane >> 3)) * LP + k0 + (lane & 7) * 8,
              &Vs[(wv * 16 + i * 8) * 64]);
    __syncthreads();
#pragma unroll
    for (int kk = 0; kk < 2; ++kk) {
      const int krd = kk * 32 + (lane >> 4) * 8;
      bf16x8 af[2], bfr[4];
#pragma unroll
      for (int m = 0; m < 2; ++m)
        af[m] = *(const bf16x8*)&Ps[(wv * 32 + m * 16 + (lane & 15)) * 64 + krd];
#pragma unroll
      for (int n = 0; n < 4; ++n)
        bfr[n] = *(const bf16x8*)&Vs[(n * 16 + (lane & 15)) * 64 + krd];
#pragma unroll
      for (int m = 0; m < 2; ++m)
#pragma unroll
        for (int n = 0; n < 4; ++n)
          acc[m][n] =
              __builtin_amdgcn_mfma_f32_16x16x32_bf16(af[m], bfr[n], acc[m][n], 0, 0, 0);
    }
    __syncthreads();
  }
  const int r0 = q0 + wv * 32 + (lane >> 4) * 4;
  const int c0 = h * 64 + (lane & 15);
#pragma unroll
  for (int m = 0; m < 2; ++m)
#pragma unroll
    for (int n = 0; n < 4; ++n)
#pragma unroll
      for (int j = 0; j < 4; ++j)
        AOb[(size_t)(b * LM + r0 + m * 16 + j) * D + c0 + n * 16] = f2bf(acc[m][n][j]);
}

// ---------------------------------------------------------------------------
// Masked softmax, in place on (B*H*LM, LP) rows.
// ---------------------------------------------------------------------------
__global__ __launch_bounds__(256) void softmax_kernel(float* __restrict__ attnp,
                                                      const int* __restrict__ mask) {
  const int row = blockIdx.x;
  const int b = row / (H * LM);
  float* p = attnp + (size_t)row * LP;
  const int* mrow = mask + b * LP;
  const int tid = threadIdx.x;

  bool mk[4]; float s[4];
  bool anyun = false;
#pragma unroll
  for (int t = 0; t < 4; ++t) {
    int k = tid + t * 256;
    mk[t] = mrow[k] != 0;
    anyun |= !mk[t];
    s[t] = p[k];
  }
  __shared__ int allm_s;
  if (tid == 0) allm_s = 1;
  __syncthreads();
  if (anyun) allm_s = 0;
  __syncthreads();
  if (allm_s && tid == 0) mk[0] = false;

  float m = -INFINITY;
#pragma unroll
  for (int t = 0; t < 4; ++t)
    if (!mk[t]) m = fmaxf(m, s[t]);
  __shared__ float red[4];
  m = wave_reduce_max(m);
  if ((tid & 63) == 0) red[tid >> 6] = m;
  __syncthreads();
  m = fmaxf(fmaxf(red[0], red[1]), fmaxf(red[2], red[3]));
  __syncthreads();

  float e[4]; float sum = 0.f;
#pragma unroll
  for (int t = 0; t < 4; ++t) {
    e[t] = mk[t] ? 0.f : expf(s[t] - m);
    sum += e[t];
  }
  sum = wave_reduce_sum(sum);
  if ((tid & 63) == 0) red[tid >> 6] = sum;
  __syncthreads();
  sum = red[0] + red[1] + red[2] + red[3];
  const float inv = 1.0f / sum;
#pragma unroll
  for (int t = 0; t < 4; ++t) p[tid + t * 256] = e[t] * inv;
}

// ---------------------------------------------------------------------------
// LayerNorm(out = LN(xa + xb) * g + be), one block per row of 768.
// ---------------------------------------------------------------------------
template <bool WB16>
__global__ __launch_bounds__(256) void ln_kernel(const float* __restrict__ xa,
                                                 const float* __restrict__ xb,
                                                 const float* __restrict__ g,
                                                 const float* __restrict__ be,
                                                 float* __restrict__ out,
                                                 u16* __restrict__ outb) {
  const int row = blockIdx.x;
  const float* pa = xa + (size_t)row * D;
  const float* pb = xb + (size_t)row * D;
  const int tid = threadIdx.x;
  float v[3]; float s = 0.f, ss = 0.f;
#pragma unroll
  for (int t = 0; t < 3; ++t) {
    int c = tid + t * 256;
    v[t] = pa[c] + pb[c];
    s += v[t]; ss += v[t] * v[t];
  }
  __shared__ float r1[4], r2[4];
  s = wave_reduce_sum(s);
  ss = wave_reduce_sum(ss);
  if ((tid & 63) == 0) { r1[tid >> 6] = s; r2[tid >> 6] = ss; }
  __syncthreads();
  s  = r1[0] + r1[1] + r1[2] + r1[3];
  ss = r2[0] + r2[1] + r2[2] + r2[3];
  const float mu  = s * (1.0f / D);
  const float var = ss * (1.0f / D) - mu * mu;
  const float inv = rsqrtf(var + 1e-5f);
#pragma unroll
  for (int t = 0; t < 3; ++t) {
    int c = tid + t * 256;
    float o = (v[t] - mu) * inv * g[c] + be[c];
    out[(size_t)row * D + c] = o;
    if (WB16) outb[(size_t)row * D + c] = f2bf(o);
  }
}

// ---------------------------------------------------------------------------
// Elementwise f32 -> bf16 (8 elems/thread; n multiple of 2048).
// ---------------------------------------------------------------------------
__global__ __launch_bounds__(256) void cast_bf16(const float* __restrict__ in,
                                                 u16* __restrict__ out) {
  const size_t i = ((size_t)blockIdx.x * 256 + threadIdx.x) * 8;
  float4 a = *(const float4*)(in + i);
  float4 c = *(const float4*)(in + i + 4);
  u16 t[8] = {f2bf(a.x), f2bf(a.y), f2bf(a.z), f2bf(a.w),
              f2bf(c.x), f2bf(c.y), f2bf(c.z), f2bf(c.w)};
  *(int4*)(out + i) = *(const int4*)t;
}

// ---------------------------------------------------------------------------
// Fused weight cast+transpose: W [K][N] f32 -> Wt [N][K] bf16, 6 weights.
// ---------------------------------------------------------------------------
struct WtDesc {
  const float* src[6];
  u16* dst[6];
  int K[6], N[6], start[6];
};

__global__ __launch_bounds__(256) void castWt(WtDesc d) {
  const int bid = blockIdx.x;
  int w = 0;
#pragma unroll
  for (int i = 1; i < 6; ++i)
    if (bid >= d.start[i]) w = i;
  const int local = bid - d.start[w];
  const int Nw = d.N[w], Kw = d.K[w];
  const int tN = Nw >> 6;
  const int n0 = (local % tN) * 64, k0 = (local / tN) * 64;
  const float* src = d.src[w];
  u16* dst = d.dst[w];

  __shared__ u16 L[64][72];
  const int t = threadIdx.x;
  const int r = t >> 3, cp = (t & 7) * 8;
#pragma unroll
  for (int it = 0; it < 2; ++it) {
    const int row = it * 32 + r;
    float4 v0 = *(const float4*)(src + (size_t)(k0 + row) * Nw + n0 + cp);
    float4 v1 = *(const float4*)(src + (size_t)(k0 + row) * Nw + n0 + cp + 4);
    L[row][cp + 0] = f2bf(v0.x); L[row][cp + 1] = f2bf(v0.y);
    L[row][cp + 2] = f2bf(v0.z); L[row][cp + 3] = f2bf(v0.w);
    L[row][cp + 4] = f2bf(v1.x); L[row][cp + 5] = f2bf(v1.y);
    L[row][cp + 6] = f2bf(v1.z); L[row][cp + 7] = f2bf(v1.w);
  }
  __syncthreads();
#pragma unroll
  for (int it = 0; it < 2; ++it) {
    const int dd = it * 32 + r;
    u16 u[8];
#pragma unroll
    for (int i = 0; i < 8; ++i) u[i] = L[cp + i][dd];
    *(int4*)(dst + (size_t)(n0 + dd) * Kw + k0 + cp) = *(const int4*)u;
  }
}

// ---------------------------------------------------------------------------
// V transpose: Vb16 [B*LP][D] bf16 -> Vt [B*H][64 dd][LP] bf16.
// grid (LP/64, B*H)
// ---------------------------------------------------------------------------
__global__ __launch_bounds__(256) void vtrans(const u16* __restrict__ Vb,
                                              u16* __restrict__ Vt) {
  const int k0 = blockIdx.x * 64;
  const int zz = blockIdx.y, b = zz / H, h = zz % H;
  __shared__ u16 L[64][72];
  const int t = threadIdx.x;
  const int r = t >> 3, cp = (t & 7) * 8;
#pragma unroll
  for (int it = 0; it < 2; ++it) {
    const int row = it * 32 + r;
    int4 v = *(const int4*)(Vb + (size_t)(b * LP + k0 + row) * D + h * 64 + cp);
    *(int4*)&L[row][cp] = v;
  }
  __syncthreads();
#pragma unroll
  for (int it = 0; it < 2; ++it) {
    const int dd = it * 32 + r;
    u16 u[8];
#pragma unroll
    for (int i = 0; i < 8; ++i) u[i] = L[cp + i][dd];
    *(int4*)(Vt + ((size_t)zz * 64 + dd) * LP + k0 + cp) = *(const int4*)u;
  }
}

}  // namespace

extern "C" void kernel_launch(void* const* d_in, const int* in_sizes, int n_in,
                              void* d_out, int out_size, void* d_ws, size_t ws_size,
                              hipStream_t stream) {
  const float* mol  = (const float*)d_in[0];
  const float* prot = (const float*)d_in[1];
  const int*   mask = (const int*)d_in[2];
  const float* Wq = (const float*)d_in[3];
  const float* Wk = (const float*)d_in[4];
  const float* Wv = (const float*)d_in[5];
  const float* Wo = (const float*)d_in[6];
  const float* bo = (const float*)d_in[7];
  const float* g1 = (const float*)d_in[8];
  const float* be1 = (const float*)d_in[9];
  const float* g2 = (const float*)d_in[10];
  const float* be2 = (const float*)d_in[11];
  const float* W1 = (const float*)d_in[12];
  const float* bf1 = (const float*)d_in[13];
  const float* W2 = (const float*)d_in[14];
  const float* bf2 = (const float*)d_in[15];

  float* outx = (float*)d_out;
  float* attn = outx + (size_t)B * LM * D;

  // ---- workspace layout (bytes), alias-packed; peak 89.7 MB ----
  char* ws = (char*)d_ws;
  u16* molb   = (u16*)(ws + 0);           // 6.3 MB ; later X1b
  u16* protb  = (u16*)(ws + 6291456);     // 12.6 MB; later WOout (f32)
  u16* Qb16   = (u16*)(ws + 18874368);    // 6.3 MB ; later AOb
  u16* Kb16   = (u16*)(ws + 25165824);    // 12.6 MB; later X1 (f32)
  u16* Vb16   = (u16*)(ws + 37748736);    // 12.6 MB; later FF (f32)
  u16* Vt     = (u16*)(ws + 50331648);    // 12.6 MB; later HIDb lower half
  u16* HIDb   = (u16*)(ws + 50331648);    // 25.2 MB (spans Vt + next region)
  u16* X1b    = (u16*)(ws + 0);
  float* WOout = (float*)(ws + 6291456);
  u16* AOb    = (u16*)(ws + 18874368);
  float* X1   = (float*)(ws + 25165824);
  float* FF   = (float*)(ws + 37748736);
  u16* Wqt = (u16*)(ws + 75497472);
  u16* Wkt = (u16*)(ws + 76677120);
  u16* Wvt = (u16*)(ws + 77856768);
  u16* Wot = (u16*)(ws + 79036416);
  u16* W1t = (u16*)(ws + 80216064);
  u16* W2t = (u16*)(ws + 84934656);

  dim3 t(256);

  // ---- casts ----
  hipLaunchKernelGGL(cast_bf16, dim3(1536), t, 0, stream, mol, molb);    // 4096*768
  hipLaunchKernelGGL(cast_bf16, dim3(3072), t, 0, stream, prot, protb);  // 8192*768
  WtDesc wd;
  wd.src[0] = Wq; wd.src[1] = Wk; wd.src[2] = Wv; wd.src[3] = Wo; wd.src[4] = W1; wd.src[5] = W2;
  wd.dst[0] = Wqt; wd.dst[1] = Wkt; wd.dst[2] = Wvt; wd.dst[3] = Wot; wd.dst[4] = W1t; wd.dst[5] = W2t;
  int Ks[6] = {768, 768, 768, 768, 768, 3072};
  int Ns[6] = {768, 768, 768, 768, 3072, 768};
  int st = 0;
  for (int i = 0; i < 6; ++i) {
    wd.K[i] = Ks[i]; wd.N[i] = Ns[i]; wd.start[i] = st;
    st += (Ns[i] / 64) * (Ks[i] / 64);
  }
  hipLaunchKernelGGL(castWt, dim3(st), t, 0, stream, wd);  // st = 1728

  // ---- projections (bf16 out) ----
  hipLaunchKernelGGL((gemm_bf16<0, false, true, false>), dim3(6, 32), t, 0, stream,
                     molb, Wqt, nullptr, nullptr, Qb16, D, D, D, D, 1.0f);
  hipLaunchKernelGGL((gemm_bf16<0, false, true, false>), dim3(6, 64), t, 0, stream,
                     protb, Wkt, nullptr, nullptr, Kb16, D, D, D, D, 1.0f);
  hipLaunchKernelGGL((gemm_bf16<0, false, true, false>), dim3(6, 64), t, 0, stream,
                     protb, Wvt, nullptr, nullptr, Vb16, D, D, D, D, 1.0f);

  // ---- attention ----
  hipLaunchKernelGGL((gemm_bf16<0, true, false, true>), dim3(8, 4, 96), t, 0, stream,
                     Qb16, Kb16, nullptr, attn, nullptr, DK, D, D, LP, 0.125f);
  hipLaunchKernelGGL(softmax_kernel, dim3(96 * 512), t, 0, stream, attn, mask);
  hipLaunchKernelGGL(vtrans, dim3(16, 96), t, 0, stream, Vb16, Vt);
  hipLaunchKernelGGL(pv_bf16, dim3(4, 96), t, 0, stream, attn, Vt, AOb);

  // ---- output proj + LN1 ----
  hipLaunchKernelGGL((gemm_bf16<1, true, false, false>), dim3(6, 32), t, 0, stream,
                     AOb, Wot, bo, WOout, nullptr, D, D, D, D, 1.0f);
  hipLaunchKernelGGL((ln_kernel<true>), dim3(4096), t, 0, stream, mol, WOout, g1, be1, X1, X1b);

  // ---- FFN ----
  hipLaunchKernelGGL((gemm_bf16<2, false, true, false>), dim3(24, 32), t, 0, stream,
                     X1b, W1t, bf1, nullptr, HIDb, D, D, D, 4 * D, 1.0f);
  hipLaunchKernelGGL((gemm_bf16<1, true, false, false>), dim3(6, 32), t, 0, stream,
                     HIDb, W2t, bf2, FF, nullptr, 4 * D, 4 * D, 4 * D, D, 1.0f);
  hipLaunchKernelGGL((ln_kernel<false>), dim3(4096), t, 0, stream, X1, FF, g2, be2, outx, nullptr);
}

// Round 3
// 349.401 us; speedup vs baseline: 4.2685x; 1.2376x over previous
//
#include <hip/hip_runtime.h>
#include <math.h>

namespace {

constexpr int D  = 768;
constexpr int H  = 12;
constexpr int B  = 8;
constexpr int LM = 512;
constexpr int LP = 1024;
constexpr int KV_LD = 1536;  // fused K|V projection row stride

typedef __attribute__((ext_vector_type(8))) short bf16x8;
typedef __attribute__((ext_vector_type(4))) float f32x4;
typedef unsigned short u16;

__device__ inline u16 f2bf(float f) {
  union { float f; unsigned u; } v;
  v.f = f;
  unsigned r = v.u + 0x7FFFu + ((v.u >> 16) & 1u);
  return (u16)(r >> 16);
}

__device__ inline void gload16(const void* g, void* l) {
  __builtin_amdgcn_global_load_lds((const __attribute__((address_space(1))) void*)g,
                                   (__attribute__((address_space(3))) void*)l,
                                   16, 0, 0);
}

__device__ inline float wave_reduce_sum(float v) {
#pragma unroll
  for (int o = 1; o < 64; o <<= 1) v += __shfl_xor(v, o, 64);
  return v;
}

// ---------------------------------------------------------------------------
// bf16 MFMA GEMM, (32*WM) x 128 tile, BK=64, 256 threads (4 waves, 2x2).
// A [M][ldA] bf16 row-major; Bt [N][ldB] bf16 row-major (B transposed).
// EPI: 0 none, 1 +bias, 2 +bias+gelu(exact).  WM: m-fragments per wave (2|4).
// ---------------------------------------------------------------------------
template <int EPI, bool OF32, bool OB16, int WM>
__global__ __launch_bounds__(256) void gemm_bf16(
    const u16* __restrict__ A, const u16* __restrict__ Bt,
    const float* __restrict__ bias, float* __restrict__ Cf,
    u16* __restrict__ Cb, int K, int ldA, int ldB, int ldC) {
  constexpr int TM = 32 * WM;
  __shared__ u16 As[TM * 64];
  __shared__ u16 Bs[128 * 64];
  const int tid = threadIdx.x, wv = tid >> 6, lane = tid & 63;
  const int bm = blockIdx.y * TM, bn = blockIdx.x * 128;
  const int wr = (wv >> 1) * (16 * WM), wc = (wv & 1) * 64;

  f32x4 acc[WM][4];
  const f32x4 z4 = {0.f, 0.f, 0.f, 0.f};
#pragma unroll
  for (int m = 0; m < WM; ++m)
#pragma unroll
    for (int n = 0; n < 4; ++n) acc[m][n] = z4;

  const u16* Ab = A + (size_t)(bm + wv * 8 * WM + (lane >> 3)) * ldA + (lane & 7) * 8;
  const u16* Bb = Bt + (size_t)(bn + wv * 32 + (lane >> 3)) * ldB + (lane & 7) * 8;

  for (int k0 = 0; k0 < K; k0 += 64) {
#pragma unroll
    for (int i = 0; i < WM; ++i)
      gload16(Ab + (size_t)i * 8 * ldA + k0, &As[(wv * 8 * WM + i * 8) * 64]);
#pragma unroll
    for (int i = 0; i < 4; ++i)
      gload16(Bb + (size_t)i * 8 * ldB + k0, &Bs[(wv * 32 + i * 8) * 64]);
    __syncthreads();
#pragma unroll
    for (int kk = 0; kk < 2; ++kk) {
      const int krd = kk * 32 + (lane >> 4) * 8;
      bf16x8 af[WM], bfr[4];
#pragma unroll
      for (int m = 0; m < WM; ++m)
        af[m] = *(const bf16x8*)&As[(wr + m * 16 + (lane & 15)) * 64 + krd];
#pragma unroll
      for (int n = 0; n < 4; ++n)
        bfr[n] = *(const bf16x8*)&Bs[(wc + n * 16 + (lane & 15)) * 64 + krd];
#pragma unroll
      for (int m = 0; m < WM; ++m)
#pragma unroll
        for (int n = 0; n < 4; ++n)
          acc[m][n] =
              __builtin_amdgcn_mfma_f32_16x16x32_bf16(af[m], bfr[n], acc[m][n], 0, 0, 0);
    }
    __syncthreads();
  }

  const int r0 = bm + wr + (lane >> 4) * 4;
  const int c0 = bn + wc + (lane & 15);
#pragma unroll
  for (int m = 0; m < WM; ++m) {
#pragma unroll
    for (int n = 0; n < 4; ++n) {
      const int c = c0 + n * 16;
      const float bv = (EPI >= 1) ? bias[c] : 0.f;
#pragma unroll
      for (int j = 0; j < 4; ++j) {
        const int r = r0 + m * 16 + j;
        float v = acc[m][n][j] + bv;
        if (EPI == 2) v = 0.5f * v * (1.f + erff(v * 0.70710678118654752f));
        if (OF32) Cf[(size_t)r * ldC + c] = v;
        if (OB16) Cb[(size_t)r * ldC + c] = f2bf(v);
      }
    }
  }
}

// ---------------------------------------------------------------------------
// Fused attention: per block = (16 q-rows, one (b,h)).  4 waves, each owns a
// 256-key slice.  QK^T (MFMA, regs) -> masked softmax (shfl + tiny LDS) ->
// write normalized f32 attn_weights (the only HBM pass) -> P to LDS bf16 ->
// PV (MFMA) -> cross-wave AO reduce -> AO bf16.
// grid: (LM/16, B*H)
// ---------------------------------------------------------------------------
__global__ __launch_bounds__(256, 2) void fattn(const u16* __restrict__ Qb,
                                                const u16* __restrict__ KVb,
                                                const u16* __restrict__ Vt,
                                                const int* __restrict__ mask,
                                                float* __restrict__ attnw,
                                                u16* __restrict__ AOb) {
  __shared__ float sadd[LP];                       // 4 KB  additive mask
  __shared__ float red[2][16][4];                  // cross-wave max/sum
  __shared__ int allm;
  __shared__ __align__(16) u16 P[4][16][264];      // 33 KB  bf16 weights
  __shared__ __align__(16) float aored[4][16][68]; // 17 KB  PV partials

  const int tid = threadIdx.x, wv = tid >> 6, lane = tid & 63;
  const int l15 = lane & 15, g = lane >> 4;
  const int zz = blockIdx.y, b = zz / H, h = zz % H;
  const int q0 = blockIdx.x * 16;

  // ---- mask prep (+ all-masked guard: unmask key 0) ----
  const int* mrow = mask + b * LP;
  int4 mv = *(const int4*)(mrow + tid * 4);
  bool anyun = !mv.x || !mv.y || !mv.z || !mv.w;
  if (tid == 0) allm = 1;
  __syncthreads();
  if (anyun) allm = 0;
  __syncthreads();
  {
    const int am = allm;
    float4 sv;
    sv.x = (mv.x && !(am && tid == 0)) ? -1e30f : 0.f;
    sv.y = mv.y ? -1e30f : 0.f;
    sv.z = mv.z ? -1e30f : 0.f;
    sv.w = mv.w ? -1e30f : 0.f;
    *(float4*)(sadd + tid * 4) = sv;
  }
  __syncthreads();

  // ---- phase 1: S = Q K^T (per-wave k-slice of 256) ----
  const u16* Qp = Qb + (size_t)(b * LM + q0 + l15) * D + h * 64 + g * 8;
  bf16x8 qf0 = *(const bf16x8*)Qp;
  bf16x8 qf1 = *(const bf16x8*)(Qp + 32);
  const int k0w = wv * 256;
  const u16* Kp = KVb + (size_t)(b * LP + k0w + l15) * KV_LD + h * 64 + g * 8;

  f32x4 acc[16];
  const f32x4 z4 = {0.f, 0.f, 0.f, 0.f};
#pragma unroll
  for (int nt = 0; nt < 16; ++nt) {
    bf16x8 kf0 = *(const bf16x8*)(Kp + (size_t)nt * 16 * KV_LD);
    bf16x8 kf1 = *(const bf16x8*)(Kp + (size_t)nt * 16 * KV_LD + 32);
    f32x4 a = z4;
    a = __builtin_amdgcn_mfma_f32_16x16x32_bf16(qf0, kf0, a, 0, 0, 0);
    a = __builtin_amdgcn_mfma_f32_16x16x32_bf16(qf1, kf1, a, 0, 0, 0);
    acc[nt] = a;
  }

  // ---- phase 2: masked softmax ----
  float mx[4] = {-1e30f, -1e30f, -1e30f, -1e30f};
#pragma unroll
  for (int nt = 0; nt < 16; ++nt) {
    const float ad = sadd[k0w + nt * 16 + l15];
#pragma unroll
    for (int r = 0; r < 4; ++r) {
      float s = acc[nt][r] * 0.125f + ad;
      acc[nt][r] = s;
      mx[r] = fmaxf(mx[r], s);
    }
  }
#pragma unroll
  for (int r = 0; r < 4; ++r) {
    mx[r] = fmaxf(mx[r], __shfl_xor(mx[r], 1, 64));
    mx[r] = fmaxf(mx[r], __shfl_xor(mx[r], 2, 64));
    mx[r] = fmaxf(mx[r], __shfl_xor(mx[r], 4, 64));
    mx[r] = fmaxf(mx[r], __shfl_xor(mx[r], 8, 64));
  }
  if (l15 == 0) {
#pragma unroll
    for (int r = 0; r < 4; ++r) red[0][g * 4 + r][wv] = mx[r];
  }
  __syncthreads();
#pragma unroll
  for (int r = 0; r < 4; ++r) {
    const int q = g * 4 + r;
    mx[r] = fmaxf(fmaxf(red[0][q][0], red[0][q][1]),
                  fmaxf(red[0][q][2], red[0][q][3]));
  }
  float sm[4] = {0.f, 0.f, 0.f, 0.f};
#pragma unroll
  for (int nt = 0; nt < 16; ++nt)
#pragma unroll
    for (int r = 0; r < 4; ++r) {
      float e = __expf(acc[nt][r] - mx[r]);
      acc[nt][r] = e;
      sm[r] += e;
    }
#pragma unroll
  for (int r = 0; r < 4; ++r) {
    sm[r] += __shfl_xor(sm[r], 1, 64);
    sm[r] += __shfl_xor(sm[r], 2, 64);
    sm[r] += __shfl_xor(sm[r], 4, 64);
    sm[r] += __shfl_xor(sm[r], 8, 64);
  }
  if (l15 == 0) {
#pragma unroll
    for (int r = 0; r < 4; ++r) red[1][g * 4 + r][wv] = sm[r];
  }
  __syncthreads();
  float inv[4];
#pragma unroll
  for (int r = 0; r < 4; ++r) {
    const int q = g * 4 + r;
    inv[r] = 1.0f / (red[1][q][0] + red[1][q][1] + red[1][q][2] + red[1][q][3]);
  }

  // ---- normalize, write attn f32 (coalesced 64B rows), stage P bf16 ----
  float* wout = attnw + ((size_t)zz * LM + q0) * LP + k0w;
#pragma unroll
  for (int nt = 0; nt < 16; ++nt)
#pragma unroll
    for (int r = 0; r < 4; ++r) {
      float w = acc[nt][r] * inv[r];
      wout[(size_t)(g * 4 + r) * LP + nt * 16 + l15] = w;
      P[wv][g * 4 + r][nt * 16 + l15] = f2bf(w);
    }
  __syncthreads();

  // ---- PV: each wave multiplies its own k-slice ----
  const u16* Vp = Vt + (size_t)zz * 64 * LP + (size_t)l15 * LP + k0w;
  f32x4 pacc[4];
#pragma unroll
  for (int dt = 0; dt < 4; ++dt) pacc[dt] = z4;
#pragma unroll
  for (int s = 0; s < 8; ++s) {
    bf16x8 pa = *(const bf16x8*)&P[wv][l15][s * 32 + g * 8];
#pragma unroll
    for (int dt = 0; dt < 4; ++dt) {
      bf16x8 vf = *(const bf16x8*)(Vp + (size_t)dt * 16 * LP + s * 32 + g * 8);
      pacc[dt] = __builtin_amdgcn_mfma_f32_16x16x32_bf16(pa, vf, pacc[dt], 0, 0, 0);
    }
  }
#pragma unroll
  for (int dt = 0; dt < 4; ++dt)
#pragma unroll
    for (int r = 0; r < 4; ++r)
      aored[wv][g * 4 + r][dt * 16 + l15] = pacc[dt][r];
  __syncthreads();

  // ---- cross-wave AO reduce + bf16 store ----
  {
    const int q = tid >> 4, c4 = (tid & 15) * 4;
    float4 o0 = *(const float4*)&aored[0][q][c4];
    float4 o1 = *(const float4*)&aored[1][q][c4];
    float4 o2 = *(const float4*)&aored[2][q][c4];
    float4 o3 = *(const float4*)&aored[3][q][c4];
    u16 ob[4] = {f2bf(o0.x + o1.x + o2.x + o3.x),
                 f2bf(o0.y + o1.y + o2.y + o3.y),
                 f2bf(o0.z + o1.z + o2.z + o3.z),
                 f2bf(o0.w + o1.w + o2.w + o3.w)};
    *(unsigned long long*)&AOb[(size_t)(b * LM + q0 + q) * D + h * 64 + c4] =
        *(const unsigned long long*)ob;
  }
}

// ---------------------------------------------------------------------------
// LayerNorm(out = LN(xa + xb) * g + be), one block per row of 768.
// ---------------------------------------------------------------------------
template <bool WB16>
__global__ __launch_bounds__(256) void ln_kernel(const float* __restrict__ xa,
                                                 const float* __restrict__ xb,
                                                 const float* __restrict__ g,
                                                 const float* __restrict__ be,
                                                 float* __restrict__ out,
                                                 u16* __restrict__ outb) {
  const int row = blockIdx.x;
  const float* pa = xa + (size_t)row * D;
  const float* pb = xb + (size_t)row * D;
  const int tid = threadIdx.x;
  float v[3]; float s = 0.f, ss = 0.f;
#pragma unroll
  for (int t = 0; t < 3; ++t) {
    int c = tid + t * 256;
    v[t] = pa[c] + pb[c];
    s += v[t]; ss += v[t] * v[t];
  }
  __shared__ float r1[4], r2[4];
  s = wave_reduce_sum(s);
  ss = wave_reduce_sum(ss);
  if ((tid & 63) == 0) { r1[tid >> 6] = s; r2[tid >> 6] = ss; }
  __syncthreads();
  s  = r1[0] + r1[1] + r1[2] + r1[3];
  ss = r2[0] + r2[1] + r2[2] + r2[3];
  const float mu  = s * (1.0f / D);
  const float var = ss * (1.0f / D) - mu * mu;
  const float inv = rsqrtf(var + 1e-5f);
#pragma unroll
  for (int t = 0; t < 3; ++t) {
    int c = tid + t * 256;
    float o = (v[t] - mu) * inv * g[c] + be[c];
    out[(size_t)row * D + c] = o;
    if (WB16) outb[(size_t)row * D + c] = f2bf(o);
  }
}

// ---------------------------------------------------------------------------
// Elementwise f32 -> bf16 (8 elems/thread).
// ---------------------------------------------------------------------------
__global__ __launch_bounds__(256) void cast_bf16(const float* __restrict__ in,
                                                 u16* __restrict__ out) {
  const size_t i = ((size_t)blockIdx.x * 256 + threadIdx.x) * 8;
  float4 a = *(const float4*)(in + i);
  float4 c = *(const float4*)(in + i + 4);
  u16 t[8] = {f2bf(a.x), f2bf(a.y), f2bf(a.z), f2bf(a.w),
              f2bf(c.x), f2bf(c.y), f2bf(c.z), f2bf(c.w)};
  *(int4*)(out + i) = *(const int4*)t;
}

// ---------------------------------------------------------------------------
// Fused weight cast+transpose: W [K][N] f32 -> Wt [N][K] bf16, 6 weights.
// ---------------------------------------------------------------------------
struct WtDesc {
  const float* src[6];
  u16* dst[6];
  int K[6], N[6], start[6];
};

__global__ __launch_bounds__(256) void castWt(WtDesc d) {
  const int bid = blockIdx.x;
  int w = 0;
#pragma unroll
  for (int i = 1; i < 6; ++i)
    if (bid >= d.start[i]) w = i;
  const int local = bid - d.start[w];
  const int Nw = d.N[w], Kw = d.K[w];
  const int tN = Nw >> 6;
  const int n0 = (local % tN) * 64, k0 = (local / tN) * 64;
  const float* src = d.src[w];
  u16* dst = d.dst[w];

  __shared__ u16 L[64][72];
  const int t = threadIdx.x;
  const int r = t >> 3, cp = (t & 7) * 8;
#pragma unroll
  for (int it = 0; it < 2; ++it) {
    const int row = it * 32 + r;
    float4 v0 = *(const float4*)(src + (size_t)(k0 + row) * Nw + n0 + cp);
    float4 v1 = *(const float4*)(src + (size_t)(k0 + row) * Nw + n0 + cp + 4);
    L[row][cp + 0] = f2bf(v0.x); L[row][cp + 1] = f2bf(v0.y);
    L[row][cp + 2] = f2bf(v0.z); L[row][cp + 3] = f2bf(v0.w);
    L[row][cp + 4] = f2bf(v1.x); L[row][cp + 5] = f2bf(v1.y);
    L[row][cp + 6] = f2bf(v1.z); L[row][cp + 7] = f2bf(v1.w);
  }
  __syncthreads();
#pragma unroll
  for (int it = 0; it < 2; ++it) {
    const int dd = it * 32 + r;
    u16 u[8];
#pragma unroll
    for (int i = 0; i < 8; ++i) u[i] = L[cp + i][dd];
    *(int4*)(dst + (size_t)(n0 + dd) * Kw + k0 + cp) = *(const int4*)u;
  }
}

// ---------------------------------------------------------------------------
// V transpose: KVb [B*LP][1536] (V = cols 768..1535) -> Vt [B*H][64][LP].
// grid (LP/64, B*H)
// ---------------------------------------------------------------------------
__global__ __launch_bounds__(256) void vtrans(const u16* __restrict__ KVb,
                                              u16* __restrict__ Vt) {
  const int k0 = blockIdx.x * 64;
  const int zz = blockIdx.y, b = zz / H, h = zz % H;
  __shared__ u16 L[64][72];
  const int t = threadIdx.x;
  const int r = t >> 3, cp = (t & 7) * 8;
#pragma unroll
  for (int it = 0; it < 2; ++it) {
    const int row = it * 32 + r;
    int4 v = *(const int4*)(KVb + (size_t)(b * LP + k0 + row) * KV_LD + 768 + h * 64 + cp);
    *(int4*)&L[row][cp] = v;
  }
  __syncthreads();
#pragma unroll
  for (int it = 0; it < 2; ++it) {
    const int dd = it * 32 + r;
    u16 u[8];
#pragma unroll
    for (int i = 0; i < 8; ++i) u[i] = L[cp + i][dd];
    *(int4*)(Vt + ((size_t)zz * 64 + dd) * LP + k0 + cp) = *(const int4*)u;
  }
}

}  // namespace

extern "C" void kernel_launch(void* const* d_in, const int* in_sizes, int n_in,
                              void* d_out, int out_size, void* d_ws, size_t ws_size,
                              hipStream_t stream) {
  const float* mol  = (const float*)d_in[0];
  const float* prot = (const float*)d_in[1];
  const int*   mask = (const int*)d_in[2];
  const float* Wq = (const float*)d_in[3];
  const float* Wk = (const float*)d_in[4];
  const float* Wv = (const float*)d_in[5];
  const float* Wo = (const float*)d_in[6];
  const float* bo = (const float*)d_in[7];
  const float* g1 = (const float*)d_in[8];
  const float* be1 = (const float*)d_in[9];
  const float* g2 = (const float*)d_in[10];
  const float* be2 = (const float*)d_in[11];
  const float* W1 = (const float*)d_in[12];
  const float* bf1 = (const float*)d_in[13];
  const float* W2 = (const float*)d_in[14];
  const float* bf2 = (const float*)d_in[15];

  float* outx = (float*)d_out;
  float* attn = outx + (size_t)B * LM * D;

  // ---- workspace layout (bytes), alias-packed; peak 89.7 MB ----
  char* ws = (char*)d_ws;
  u16* molb   = (u16*)(ws + 0);           // dead after Qproj -> AOb
  u16* protb  = (u16*)(ws + 6291456);     // dead after KVproj -> WOout
  u16* Qb16   = (u16*)(ws + 18874368);    // dead after fattn -> X1
  u16* KVb16  = (u16*)(ws + 25165824);    // dead after fattn/vtrans
  u16* Vt     = (u16*)(ws + 50331648);    // dead after fattn
  u16* AOb    = (u16*)(ws + 0);
  float* WOout = (float*)(ws + 6291456);
  float* X1   = (float*)(ws + 18874368);
  u16* X1b    = (u16*)(ws + 31457280);
  u16* HIDb   = (u16*)(ws + 37748736);
  float* FF   = (float*)(ws + 62914560);
  u16* Wqt  = (u16*)(ws + 75497472);
  u16* Wkvt = (u16*)(ws + 76677120);      // rows 0..767 = Wk^T, 768..1535 = Wv^T
  u16* Wot  = (u16*)(ws + 79036416);
  u16* W1t  = (u16*)(ws + 80216064);
  u16* W2t  = (u16*)(ws + 84934656);

  dim3 t(256);

  // ---- casts ----
  hipLaunchKernelGGL(cast_bf16, dim3(1536), t, 0, stream, mol, molb);
  hipLaunchKernelGGL(cast_bf16, dim3(3072), t, 0, stream, prot, protb);
  WtDesc wd;
  wd.src[0] = Wq; wd.src[1] = Wk; wd.src[2] = Wv; wd.src[3] = Wo; wd.src[4] = W1; wd.src[5] = W2;
  wd.dst[0] = Wqt; wd.dst[1] = Wkvt; wd.dst[2] = Wkvt + 768 * 768; wd.dst[3] = Wot;
  wd.dst[4] = W1t; wd.dst[5] = W2t;
  int Ks[6] = {768, 768, 768, 768, 768, 3072};
  int Ns[6] = {768, 768, 768, 768, 3072, 768};
  int st = 0;
  for (int i = 0; i < 6; ++i) {
    wd.K[i] = Ks[i]; wd.N[i] = Ns[i]; wd.start[i] = st;
    st += (Ns[i] / 64) * (Ks[i] / 64);
  }
  hipLaunchKernelGGL(castWt, dim3(st), t, 0, stream, wd);

  // ---- projections ----
  hipLaunchKernelGGL((gemm_bf16<0, false, true, 2>), dim3(6, 64), t, 0, stream,
                     molb, Wqt, nullptr, nullptr, Qb16, D, D, D, D);
  hipLaunchKernelGGL((gemm_bf16<0, false, true, 4>), dim3(12, 64), t, 0, stream,
                     protb, Wkvt, nullptr, nullptr, KVb16, D, D, D, KV_LD);
  hipLaunchKernelGGL(vtrans, dim3(16, 96), t, 0, stream, KVb16, Vt);

  // ---- fused attention ----
  hipLaunchKernelGGL(fattn, dim3(32, 96), t, 0, stream, Qb16, KVb16, Vt, mask, attn, AOb);

  // ---- output proj + LN1 ----
  hipLaunchKernelGGL((gemm_bf16<1, true, false, 2>), dim3(6, 64), t, 0, stream,
                     AOb, Wot, bo, WOout, nullptr, D, D, D, D);
  hipLaunchKernelGGL((ln_kernel<true>), dim3(4096), t, 0, stream, mol, WOout, g1, be1, X1, X1b);

  // ---- FFN ----
  hipLaunchKernelGGL((gemm_bf16<2, false, true, 4>), dim3(24, 32), t, 0, stream,
                     X1b, W1t, bf1, nullptr, HIDb, D, D, D, 4 * D);
  hipLaunchKernelGGL((gemm_bf16<1, true, false, 2>), dim3(6, 64), t, 0, stream,
                     HIDb, W2t, bf2, FF, nullptr, 4 * D, 4 * D, 4 * D, D);
  hipLaunchKernelGGL((ln_kernel<false>), dim3(4096), t, 0, stream, X1, FF, g2, be2, outx, nullptr);
}

// Round 4
// 338.575 us; speedup vs baseline: 4.4050x; 1.0320x over previous
//
#include <hip/hip_runtime.h>
#include <math.h>

namespace {

constexpr int D  = 768;
constexpr int H  = 12;
constexpr int B  = 8;
constexpr int LM = 512;
constexpr int LP = 1024;
constexpr int KV_LD = 1536;  // fused K|V projection row stride

typedef __attribute__((ext_vector_type(8))) short bf16x8;
typedef __attribute__((ext_vector_type(4))) float f32x4;
typedef unsigned short u16;

__device__ inline u16 f2bf(float f) {
  union { float f; unsigned u; } v;
  v.f = f;
  unsigned r = v.u + 0x7FFFu + ((v.u >> 16) & 1u);
  return (u16)(r >> 16);
}

__device__ inline void gload16(const void* g, void* l) {
  __builtin_amdgcn_global_load_lds((const __attribute__((address_space(1))) void*)g,
                                   (__attribute__((address_space(3))) void*)l,
                                   16, 0, 0);
}

__device__ inline float wave_reduce_sum(float v) {
#pragma unroll
  for (int o = 1; o < 64; o <<= 1) v += __shfl_xor(v, o, 64);
  return v;
}

// ---------------------------------------------------------------------------
// bf16 MFMA GEMM, (32*WM) x 128 tile, BK=64, 256 threads (4 waves, 2x2).
// A [M][ldA] bf16 row-major; Bt [N][ldB] bf16 row-major (B transposed).
// EPI: 0 none, 1 +bias, 2 +bias+gelu(exact).  WM: m-fragments per wave (2|4).
// XCD-aware block swizzle (bijective; all call-site grids are %8==0).
// ---------------------------------------------------------------------------
template <int EPI, bool OF32, bool OB16, int WM>
__global__ __launch_bounds__(256) void gemm_bf16(
    const u16* __restrict__ A, const u16* __restrict__ Bt,
    const float* __restrict__ bias, float* __restrict__ Cf,
    u16* __restrict__ Cb, int K, int ldA, int ldB, int ldC) {
  constexpr int TM = 32 * WM;
  __shared__ u16 As[TM * 64];
  __shared__ u16 Bs[128 * 64];
  const int tid = threadIdx.x, wv = tid >> 6, lane = tid & 63;

  int bx, by;
  {
    const int total = gridDim.x * gridDim.y;
    const int flat = blockIdx.y * gridDim.x + blockIdx.x;
    if ((total & 7) == 0) {
      const int s = (flat & 7) * (total >> 3) + (flat >> 3);
      bx = s % gridDim.x;
      by = s / gridDim.x;
    } else {
      bx = blockIdx.x;
      by = blockIdx.y;
    }
  }
  const int bm = by * TM, bn = bx * 128;
  const int wr = (wv >> 1) * (16 * WM), wc = (wv & 1) * 64;

  f32x4 acc[WM][4];
  const f32x4 z4 = {0.f, 0.f, 0.f, 0.f};
#pragma unroll
  for (int m = 0; m < WM; ++m)
#pragma unroll
    for (int n = 0; n < 4; ++n) acc[m][n] = z4;

  const u16* Ab = A + (size_t)(bm + wv * 8 * WM + (lane >> 3)) * ldA + (lane & 7) * 8;
  const u16* Bb = Bt + (size_t)(bn + wv * 32 + (lane >> 3)) * ldB + (lane & 7) * 8;

  for (int k0 = 0; k0 < K; k0 += 64) {
#pragma unroll
    for (int i = 0; i < WM; ++i)
      gload16(Ab + (size_t)i * 8 * ldA + k0, &As[(wv * 8 * WM + i * 8) * 64]);
#pragma unroll
    for (int i = 0; i < 4; ++i)
      gload16(Bb + (size_t)i * 8 * ldB + k0, &Bs[(wv * 32 + i * 8) * 64]);
    __syncthreads();
#pragma unroll
    for (int kk = 0; kk < 2; ++kk) {
      const int krd = kk * 32 + (lane >> 4) * 8;
      bf16x8 af[WM], bfr[4];
#pragma unroll
      for (int m = 0; m < WM; ++m)
        af[m] = *(const bf16x8*)&As[(wr + m * 16 + (lane & 15)) * 64 + krd];
#pragma unroll
      for (int n = 0; n < 4; ++n)
        bfr[n] = *(const bf16x8*)&Bs[(wc + n * 16 + (lane & 15)) * 64 + krd];
#pragma unroll
      for (int m = 0; m < WM; ++m)
#pragma unroll
        for (int n = 0; n < 4; ++n)
          acc[m][n] =
              __builtin_amdgcn_mfma_f32_16x16x32_bf16(af[m], bfr[n], acc[m][n], 0, 0, 0);
    }
    __syncthreads();
  }

  const int r0 = bm + wr + (lane >> 4) * 4;
  const int c0 = bn + wc + (lane & 15);
#pragma unroll
  for (int m = 0; m < WM; ++m) {
#pragma unroll
    for (int n = 0; n < 4; ++n) {
      const int c = c0 + n * 16;
      const float bv = (EPI >= 1) ? bias[c] : 0.f;
#pragma unroll
      for (int j = 0; j < 4; ++j) {
        const int r = r0 + m * 16 + j;
        float v = acc[m][n][j] + bv;
        if (EPI == 2) v = 0.5f * v * (1.f + erff(v * 0.70710678118654752f));
        if (OF32) Cf[(size_t)r * ldC + c] = v;
        if (OB16) Cb[(size_t)r * ldC + c] = f2bf(v);
      }
    }
  }
}

// ---------------------------------------------------------------------------
// Fused attention: per block = (16 q-rows, one (b,h)).  4 waves, each owns a
// 256-key slice.  QK^T (MFMA, regs) -> masked softmax (shfl + tiny LDS) ->
// write normalized f32 attn_weights (the only HBM pass) -> P to LDS bf16 ->
// PV (MFMA) -> cross-wave AO reduce -> AO bf16.
// 1D grid 3072 with bijective XCD swizzle: all 32 q-tiles of one (b,h) land
// on the same XCD so the K/V head-slice is fetched once per XCD L2.
// LDS: per-wave P (bf16 weights) and ao (PV partials) overlap in a union —
// ao writes depend transitively on all P reads, so no barrier needed between.
// ---------------------------------------------------------------------------
union WaveMem {
  u16 P[16][264];     // 8448 B
  float ao[16][68];   // 4352 B
};

__global__ __launch_bounds__(256, 4) void fattn(const u16* __restrict__ Qb,
                                                const u16* __restrict__ KVb,
                                                const u16* __restrict__ Vt,
                                                const int* __restrict__ mask,
                                                float* __restrict__ attnw,
                                                u16* __restrict__ AOb) {
  __shared__ float sadd[LP];                      // 4 KB  additive mask
  __shared__ float red[2][16][4];                 // cross-wave max/sum
  __shared__ int allm;
  __shared__ __align__(16) WaveMem wm[4];         // 33 KB

  const int tid = threadIdx.x, wv = tid >> 6, lane = tid & 63;
  const int l15 = lane & 15, g = lane >> 4;
  const int flat = blockIdx.x;                    // 0..3071
  const int idx = (flat & 7) * 384 + (flat >> 3); // XCD chunking (3072/8=384)
  const int q0 = (idx & 31) * 16;
  const int zz = idx >> 5;
  const int b = zz / H, h = zz % H;

  // ---- mask prep (+ all-masked guard: unmask key 0) ----
  const int* mrow = mask + b * LP;
  int4 mv = *(const int4*)(mrow + tid * 4);
  bool anyun = !mv.x || !mv.y || !mv.z || !mv.w;
  if (tid == 0) allm = 1;
  __syncthreads();
  if (anyun) allm = 0;
  __syncthreads();
  {
    const int am = allm;
    float4 sv;
    sv.x = (mv.x && !(am && tid == 0)) ? -1e30f : 0.f;
    sv.y = mv.y ? -1e30f : 0.f;
    sv.z = mv.z ? -1e30f : 0.f;
    sv.w = mv.w ? -1e30f : 0.f;
    *(float4*)(sadd + tid * 4) = sv;
  }
  __syncthreads();

  // ---- phase 1: S = Q K^T (per-wave k-slice of 256) ----
  const u16* Qp = Qb + (size_t)(b * LM + q0 + l15) * D + h * 64 + g * 8;
  bf16x8 qf0 = *(const bf16x8*)Qp;
  bf16x8 qf1 = *(const bf16x8*)(Qp + 32);
  const int k0w = wv * 256;
  const u16* Kp = KVb + (size_t)(b * LP + k0w + l15) * KV_LD + h * 64 + g * 8;

  f32x4 acc[16];
  const f32x4 z4 = {0.f, 0.f, 0.f, 0.f};
#pragma unroll
  for (int nt = 0; nt < 16; ++nt) {
    bf16x8 kf0 = *(const bf16x8*)(Kp + (size_t)nt * 16 * KV_LD);
    bf16x8 kf1 = *(const bf16x8*)(Kp + (size_t)nt * 16 * KV_LD + 32);
    f32x4 a = z4;
    a = __builtin_amdgcn_mfma_f32_16x16x32_bf16(qf0, kf0, a, 0, 0, 0);
    a = __builtin_amdgcn_mfma_f32_16x16x32_bf16(qf1, kf1, a, 0, 0, 0);
    acc[nt] = a;
  }

  // ---- phase 2: masked softmax ----
  float mx[4] = {-1e30f, -1e30f, -1e30f, -1e30f};
#pragma unroll
  for (int nt = 0; nt < 16; ++nt) {
    const float ad = sadd[k0w + nt * 16 + l15];
#pragma unroll
    for (int r = 0; r < 4; ++r) {
      float s = acc[nt][r] * 0.125f + ad;
      acc[nt][r] = s;
      mx[r] = fmaxf(mx[r], s);
    }
  }
#pragma unroll
  for (int r = 0; r < 4; ++r) {
    mx[r] = fmaxf(mx[r], __shfl_xor(mx[r], 1, 64));
    mx[r] = fmaxf(mx[r], __shfl_xor(mx[r], 2, 64));
    mx[r] = fmaxf(mx[r], __shfl_xor(mx[r], 4, 64));
    mx[r] = fmaxf(mx[r], __shfl_xor(mx[r], 8, 64));
  }
  if (l15 == 0) {
#pragma unroll
    for (int r = 0; r < 4; ++r) red[0][g * 4 + r][wv] = mx[r];
  }
  __syncthreads();
#pragma unroll
  for (int r = 0; r < 4; ++r) {
    const int q = g * 4 + r;
    mx[r] = fmaxf(fmaxf(red[0][q][0], red[0][q][1]),
                  fmaxf(red[0][q][2], red[0][q][3]));
  }
  float sm[4] = {0.f, 0.f, 0.f, 0.f};
#pragma unroll
  for (int nt = 0; nt < 16; ++nt)
#pragma unroll
    for (int r = 0; r < 4; ++r) {
      float e = __expf(acc[nt][r] - mx[r]);
      acc[nt][r] = e;
      sm[r] += e;
    }
#pragma unroll
  for (int r = 0; r < 4; ++r) {
    sm[r] += __shfl_xor(sm[r], 1, 64);
    sm[r] += __shfl_xor(sm[r], 2, 64);
    sm[r] += __shfl_xor(sm[r], 4, 64);
    sm[r] += __shfl_xor(sm[r], 8, 64);
  }
  if (l15 == 0) {
#pragma unroll
    for (int r = 0; r < 4; ++r) red[1][g * 4 + r][wv] = sm[r];
  }
  __syncthreads();
  float inv[4];
#pragma unroll
  for (int r = 0; r < 4; ++r) {
    const int q = g * 4 + r;
    inv[r] = 1.0f / (red[1][q][0] + red[1][q][1] + red[1][q][2] + red[1][q][3]);
  }

  // ---- normalize, write attn f32 (the only HBM pass), stage P bf16 ----
  float* wout = attnw + ((size_t)zz * LM + q0) * LP + k0w;
#pragma unroll
  for (int nt = 0; nt < 16; ++nt)
#pragma unroll
    for (int r = 0; r < 4; ++r) {
      float w = acc[nt][r] * inv[r];
      wout[(size_t)(g * 4 + r) * LP + nt * 16 + l15] = w;
      wm[wv].P[g * 4 + r][nt * 16 + l15] = f2bf(w);
    }
  // no barrier: each wave reads only its own wm[wv].P below.

  // ---- PV: each wave multiplies its own k-slice ----
  const u16* Vp = Vt + (size_t)zz * 64 * LP + (size_t)l15 * LP + k0w;
  f32x4 pacc[4];
#pragma unroll
  for (int dt = 0; dt < 4; ++dt) pacc[dt] = z4;
#pragma unroll
  for (int s = 0; s < 8; ++s) {
    bf16x8 pa = *(const bf16x8*)&wm[wv].P[l15][s * 32 + g * 8];
#pragma unroll
    for (int dt = 0; dt < 4; ++dt) {
      bf16x8 vf = *(const bf16x8*)(Vp + (size_t)dt * 16 * LP + s * 32 + g * 8);
      pacc[dt] = __builtin_amdgcn_mfma_f32_16x16x32_bf16(pa, vf, pacc[dt], 0, 0, 0);
    }
  }
  // overlay ao on P: every ao element depends (through pacc) on all P reads.
#pragma unroll
  for (int dt = 0; dt < 4; ++dt)
#pragma unroll
    for (int r = 0; r < 4; ++r)
      wm[wv].ao[g * 4 + r][dt * 16 + l15] = pacc[dt][r];
  __syncthreads();

  // ---- cross-wave AO reduce + bf16 store ----
  {
    const int q = tid >> 4, c4 = (tid & 15) * 4;
    float4 o0 = *(const float4*)&wm[0].ao[q][c4];
    float4 o1 = *(const float4*)&wm[1].ao[q][c4];
    float4 o2 = *(const float4*)&wm[2].ao[q][c4];
    float4 o3 = *(const float4*)&wm[3].ao[q][c4];
    u16 ob[4] = {f2bf(o0.x + o1.x + o2.x + o3.x),
                 f2bf(o0.y + o1.y + o2.y + o3.y),
                 f2bf(o0.z + o1.z + o2.z + o3.z),
                 f2bf(o0.w + o1.w + o2.w + o3.w)};
    *(unsigned long long*)&AOb[(size_t)(b * LM + q0 + q) * D + h * 64 + c4] =
        *(const unsigned long long*)ob;
  }
}

// ---------------------------------------------------------------------------
// LayerNorm(out = LN(xa + xb) * g + be), one block per row of 768.
// ---------------------------------------------------------------------------
template <bool WB16>
__global__ __launch_bounds__(256) void ln_kernel(const float* __restrict__ xa,
                                                 const float* __restrict__ xb,
                                                 const float* __restrict__ g,
                                                 const float* __restrict__ be,
                                                 float* __restrict__ out,
                                                 u16* __restrict__ outb) {
  const int row = blockIdx.x;
  const float* pa = xa + (size_t)row * D;
  const float* pb = xb + (size_t)row * D;
  const int tid = threadIdx.x;
  float v[3]; float s = 0.f, ss = 0.f;
#pragma unroll
  for (int t = 0; t < 3; ++t) {
    int c = tid + t * 256;
    v[t] = pa[c] + pb[c];
    s += v[t]; ss += v[t] * v[t];
  }
  __shared__ float r1[4], r2[4];
  s = wave_reduce_sum(s);
  ss = wave_reduce_sum(ss);
  if ((tid & 63) == 0) { r1[tid >> 6] = s; r2[tid >> 6] = ss; }
  __syncthreads();
  s  = r1[0] + r1[1] + r1[2] + r1[3];
  ss = r2[0] + r2[1] + r2[2] + r2[3];
  const float mu  = s * (1.0f / D);
  const float var = ss * (1.0f / D) - mu * mu;
  const float inv = rsqrtf(var + 1e-5f);
#pragma unroll
  for (int t = 0; t < 3; ++t) {
    int c = tid + t * 256;
    float o = (v[t] - mu) * inv * g[c] + be[c];
    out[(size_t)row * D + c] = o;
    if (WB16) outb[(size_t)row * D + c] = f2bf(o);
  }
}

// ---------------------------------------------------------------------------
// Elementwise f32 -> bf16 (8 elems/thread).
// ---------------------------------------------------------------------------
__global__ __launch_bounds__(256) void cast_bf16(const float* __restrict__ in,
                                                 u16* __restrict__ out) {
  const size_t i = ((size_t)blockIdx.x * 256 + threadIdx.x) * 8;
  float4 a = *(const float4*)(in + i);
  float4 c = *(const float4*)(in + i + 4);
  u16 t[8] = {f2bf(a.x), f2bf(a.y), f2bf(a.z), f2bf(a.w),
              f2bf(c.x), f2bf(c.y), f2bf(c.z), f2bf(c.w)};
  *(int4*)(out + i) = *(const int4*)t;
}

// ---------------------------------------------------------------------------
// Fused weight cast+transpose: W [K][N] f32 -> Wt [N][K] bf16, 6 weights.
// ---------------------------------------------------------------------------
struct WtDesc {
  const float* src[6];
  u16* dst[6];
  int K[6], N[6], start[6];
};

__global__ __launch_bounds__(256) void castWt(WtDesc d) {
  const int bid = blockIdx.x;
  int w = 0;
#pragma unroll
  for (int i = 1; i < 6; ++i)
    if (bid >= d.start[i]) w = i;
  const int local = bid - d.start[w];
  const int Nw = d.N[w], Kw = d.K[w];
  const int tN = Nw >> 6;
  const int n0 = (local % tN) * 64, k0 = (local / tN) * 64;
  const float* src = d.src[w];
  u16* dst = d.dst[w];

  __shared__ u16 L[64][72];
  const int t = threadIdx.x;
  const int r = t >> 3, cp = (t & 7) * 8;
#pragma unroll
  for (int it = 0; it < 2; ++it) {
    const int row = it * 32 + r;
    float4 v0 = *(const float4*)(src + (size_t)(k0 + row) * Nw + n0 + cp);
    float4 v1 = *(const float4*)(src + (size_t)(k0 + row) * Nw + n0 + cp + 4);
    L[row][cp + 0] = f2bf(v0.x); L[row][cp + 1] = f2bf(v0.y);
    L[row][cp + 2] = f2bf(v0.z); L[row][cp + 3] = f2bf(v0.w);
    L[row][cp + 4] = f2bf(v1.x); L[row][cp + 5] = f2bf(v1.y);
    L[row][cp + 6] = f2bf(v1.z); L[row][cp + 7] = f2bf(v1.w);
  }
  __syncthreads();
#pragma unroll
  for (int it = 0; it < 2; ++it) {
    const int dd = it * 32 + r;
    u16 u[8];
#pragma unroll
    for (int i = 0; i < 8; ++i) u[i] = L[cp + i][dd];
    *(int4*)(dst + (size_t)(n0 + dd) * Kw + k0 + cp) = *(const int4*)u;
  }
}

// ---------------------------------------------------------------------------
// V transpose: KVb [B*LP][1536] (V = cols 768..1535) -> Vt [B*H][64][LP].
// grid (LP/64, B*H)
// ---------------------------------------------------------------------------
__global__ __launch_bounds__(256) void vtrans(const u16* __restrict__ KVb,
                                              u16* __restrict__ Vt) {
  const int k0 = blockIdx.x * 64;
  const int zz = blockIdx.y, b = zz / H, h = zz % H;
  __shared__ u16 L[64][72];
  const int t = threadIdx.x;
  const int r = t >> 3, cp = (t & 7) * 8;
#pragma unroll
  for (int it = 0; it < 2; ++it) {
    const int row = it * 32 + r;
    int4 v = *(const int4*)(KVb + (size_t)(b * LP + k0 + row) * KV_LD + 768 + h * 64 + cp);
    *(int4*)&L[row][cp] = v;
  }
  __syncthreads();
#pragma unroll
  for (int it = 0; it < 2; ++it) {
    const int dd = it * 32 + r;
    u16 u[8];
#pragma unroll
    for (int i = 0; i < 8; ++i) u[i] = L[cp + i][dd];
    *(int4*)(Vt + ((size_t)zz * 64 + dd) * LP + k0 + cp) = *(const int4*)u;
  }
}

}  // namespace

extern "C" void kernel_launch(void* const* d_in, const int* in_sizes, int n_in,
                              void* d_out, int out_size, void* d_ws, size_t ws_size,
                              hipStream_t stream) {
  const float* mol  = (const float*)d_in[0];
  const float* prot = (const float*)d_in[1];
  const int*   mask = (const int*)d_in[2];
  const float* Wq = (const float*)d_in[3];
  const float* Wk = (const float*)d_in[4];
  const float* Wv = (const float*)d_in[5];
  const float* Wo = (const float*)d_in[6];
  const float* bo = (const float*)d_in[7];
  const float* g1 = (const float*)d_in[8];
  const float* be1 = (const float*)d_in[9];
  const float* g2 = (const float*)d_in[10];
  const float* be2 = (const float*)d_in[11];
  const float* W1 = (const float*)d_in[12];
  const float* bf1 = (const float*)d_in[13];
  const float* W2 = (const float*)d_in[14];
  const float* bf2 = (const float*)d_in[15];

  float* outx = (float*)d_out;
  float* attn = outx + (size_t)B * LM * D;

  // ---- workspace layout (bytes), alias-packed; peak 89.7 MB ----
  char* ws = (char*)d_ws;
  u16* molb   = (u16*)(ws + 0);           // dead after Qproj -> AOb
  u16* protb  = (u16*)(ws + 6291456);     // dead after KVproj -> WOout
  u16* Qb16   = (u16*)(ws + 18874368);    // dead after fattn -> X1
  u16* KVb16  = (u16*)(ws + 25165824);    // dead after fattn/vtrans
  u16* Vt     = (u16*)(ws + 50331648);    // dead after fattn
  u16* AOb    = (u16*)(ws + 0);
  float* WOout = (float*)(ws + 6291456);
  float* X1   = (float*)(ws + 18874368);
  u16* X1b    = (u16*)(ws + 31457280);
  u16* HIDb   = (u16*)(ws + 37748736);
  float* FF   = (float*)(ws + 62914560);
  u16* Wqt  = (u16*)(ws + 75497472);
  u16* Wkvt = (u16*)(ws + 76677120);      // rows 0..767 = Wk^T, 768..1535 = Wv^T
  u16* Wot  = (u16*)(ws + 79036416);
  u16* W1t  = (u16*)(ws + 80216064);
  u16* W2t  = (u16*)(ws + 84934656);

  dim3 t(256);

  // ---- casts ----
  hipLaunchKernelGGL(cast_bf16, dim3(1536), t, 0, stream, mol, molb);
  hipLaunchKernelGGL(cast_bf16, dim3(3072), t, 0, stream, prot, protb);
  WtDesc wd;
  wd.src[0] = Wq; wd.src[1] = Wk; wd.src[2] = Wv; wd.src[3] = Wo; wd.src[4] = W1; wd.src[5] = W2;
  wd.dst[0] = Wqt; wd.dst[1] = Wkvt; wd.dst[2] = Wkvt + 768 * 768; wd.dst[3] = Wot;
  wd.dst[4] = W1t; wd.dst[5] = W2t;
  int Ks[6] = {768, 768, 768, 768, 768, 3072};
  int Ns[6] = {768, 768, 768, 768, 3072, 768};
  int st = 0;
  for (int i = 0; i < 6; ++i) {
    wd.K[i] = Ks[i]; wd.N[i] = Ns[i]; wd.start[i] = st;
    st += (Ns[i] / 64) * (Ks[i] / 64);
  }
  hipLaunchKernelGGL(castWt, dim3(st), t, 0, stream, wd);

  // ---- projections ----
  hipLaunchKernelGGL((gemm_bf16<0, false, true, 2>), dim3(6, 64), t, 0, stream,
                     molb, Wqt, nullptr, nullptr, Qb16, D, D, D, D);
  hipLaunchKernelGGL((gemm_bf16<0, false, true, 4>), dim3(12, 64), t, 0, stream,
                     protb, Wkvt, nullptr, nullptr, KVb16, D, D, D, KV_LD);
  hipLaunchKernelGGL(vtrans, dim3(16, 96), t, 0, stream, KVb16, Vt);

  // ---- fused attention (1D grid, XCD-swizzled) ----
  hipLaunchKernelGGL(fattn, dim3(3072), t, 0, stream, Qb16, KVb16, Vt, mask, attn, AOb);

  // ---- output proj + LN1 ----
  hipLaunchKernelGGL((gemm_bf16<1, true, false, 2>), dim3(6, 64), t, 0, stream,
                     AOb, Wot, bo, WOout, nullptr, D, D, D, D);
  hipLaunchKernelGGL((ln_kernel<true>), dim3(4096), t, 0, stream, mol, WOout, g1, be1, X1, X1b);

  // ---- FFN ----
  hipLaunchKernelGGL((gemm_bf16<2, false, true, 4>), dim3(24, 32), t, 0, stream,
                     X1b, W1t, bf1, nullptr, HIDb, D, D, D, 4 * D);
  hipLaunchKernelGGL((gemm_bf16<1, true, false, 2>), dim3(6, 64), t, 0, stream,
                     HIDb, W2t, bf2, FF, nullptr, 4 * D, 4 * D, 4 * D, D);
  hipLaunchKernelGGL((ln_kernel<false>), dim3(4096), t, 0, stream, X1, FF, g2, be2, outx, nullptr);
}